// Round 1
// baseline (449.861 us; speedup 1.0000x reference)
//
#include <hip/hip_runtime.h>
#include <hip/hip_bf16.h>

// Problem constants (setup_inputs fixed: B=16, z_dim=64, H=W=32, M=4096)
#define ZD   64
#define MM   4096
#define NN   16384
#define HWSZ 1024
#define BB   16

typedef __bf16 bf16x8 __attribute__((ext_vector_type(8)));
typedef float  f32x4  __attribute__((ext_vector_type(4)));

#define EMA_C 0.999f
#define EPS_C 1e-8f

// ---------------------------------------------------------------------------
// k_prep (merged): blocks [0,256): z transpose->bf16 + zn2
//                  blocks [256,1280): e->bf16 + en2 + accumulator init
// ---------------------------------------------------------------------------
__global__ __launch_bounds__(256) void k_prep(const float* __restrict__ z,
                                              const float* __restrict__ e,
                                              __hip_bfloat16* __restrict__ zf,
                                              __hip_bfloat16* __restrict__ ebf,
                                              float* __restrict__ zn2,
                                              float* __restrict__ en2,
                                              unsigned* __restrict__ bmax,
                                              unsigned* __restrict__ dmin,
                                              float* __restrict__ sume) {
    __shared__ float tile[64][65];
    __shared__ float part[4][64];
    int blk = blockIdx.x;
    int tid = threadIdx.x;
    if (blk < 256) {
        // ---- z prep: b = blk>>4, hw-tile = blk&15 ----
        int b   = blk >> 4;
        int hw0 = (blk & 15) * 64;
        int tx = tid & 63, ty = tid >> 6;
        const float* zp = z + (size_t)b * (ZD * HWSZ);
#pragma unroll
        for (int kk = 0; kk < 16; kk++) {
            int k = kk * 4 + ty;
            tile[k][tx] = zp[(size_t)k * HWSZ + hw0 + tx];  // coalesced
        }
        __syncthreads();
#pragma unroll
        for (int i = 0; i < 16; i++) {   // coalesced bf16 row writes
            int li = tid + i * 256;
            int ln = li >> 6, lk = li & 63;
            int n = b * HWSZ + hw0 + ln;
            zf[(size_t)n * ZD + lk] = __float2bfloat16(tile[lk][ln]);
        }
        float s = 0.f;
#pragma unroll
        for (int kk = 0; kk < 16; kk++) {
            float q = __bfloat162float(__float2bfloat16(tile[ty * 1 + kk * 4][tx]));
            s += q * q;
        }
        part[ty][tx] = s;
        __syncthreads();
        if (tid < 64) {
            float t = part[0][tid] + part[1][tid] + part[2][tid] + part[3][tid];
            zn2[b * HWSZ + hw0 + tid] = t;
        }
    } else {
        // ---- e prep + init ----
        int eb  = blk - 256;            // 0..1023
        int gid = eb * 256 + tid;
        if (gid < MM) {                 // ws is poisoned 0xAA each launch
            bmax[gid] = 0u;             // belong*d >= 0 -> uint max works
            dmin[gid] = 0x7f800000u;    // +inf
            sume[gid] = 0.f;
        }
        int wave = tid >> 6, lane = tid & 63;
        int row = eb * 4 + wave;
        if (row < MM) {
            float v = e[row * ZD + lane];
            __hip_bfloat16 b16 = __float2bfloat16(v);
            ebf[row * ZD + lane] = b16;
            float q = __bfloat162float(b16);  // norm from quantized value
            float s = q * q;
            for (int off = 32; off; off >>= 1) s += __shfl_xor(s, off);
            if (lane == 0) en2[row] = s;
        }
    }
}

// ---------------------------------------------------------------------------
// k_pass1: SWAPPED operand order (A = ebf rows m, B = zf rows n) so that
// D: row = m = lq*4 + reg ; col = n = l16.
// Each block now PERSISTS over 4 n-tiles (grid 8192 -> 2048 blocks):
//  - A-fragments (ebf) + en2 hoisted out of the loop
//  - running max/min kept in REGISTERS across tiles (tracking b^2*d^2 and
//    d^2 -> sqrt deferred from 67M elements to 16/block)
//  - shuffle tree + shared reduce + global atomics ONCE per block
//    (global atomicMax/Min: 1.05M -> 262K)
// ---------------------------------------------------------------------------
__global__ __launch_bounds__(256) void k_pass1(const __hip_bfloat16* __restrict__ zf,
                                               const __hip_bfloat16* __restrict__ ebf,
                                               const float* __restrict__ zn2,
                                               const float* __restrict__ en2,
                                               const float* __restrict__ belong,
                                               unsigned* __restrict__ bmax,
                                               unsigned* __restrict__ dmin) {
    int tid = threadIdx.x;
    int wave = tid >> 6, lane = tid & 63;
    int l16 = lane & 15, lq = lane >> 4;
    int wm = wave & 1, wn = wave >> 1;
    int m0 = blockIdx.x * 64 + wm * 32;

    const bf16x8* ebv = reinterpret_cast<const bf16x8*>(ebf);
    const bf16x8* zfv = reinterpret_cast<const bf16x8*>(zf);

    // n-invariant: A fragments (ebf rows m) + en2
    bf16x8 Af[2][2];
#pragma unroll
    for (int im = 0; im < 2; im++)
#pragma unroll
        for (int h = 0; h < 2; h++)
            Af[im][h] = ebv[(size_t)(m0 + im * 16 + l16) * 8 + h * 4 + lq];
    f32x4 en2v[2];
#pragma unroll
    for (int im = 0; im < 2; im++)
        en2v[im] = *reinterpret_cast<const f32x4*>(en2 + m0 + im * 16 + lq * 4);

    float vmax2[2][4], vmin2[2][4];   // (belong*d)^2 and d^2 running extrema
#pragma unroll
    for (int im = 0; im < 2; im++)
#pragma unroll
        for (int r = 0; r < 4; r++) { vmax2[im][r] = 0.f; vmin2[im][r] = 3.4e38f; }

#pragma unroll 1
    for (int it = 0; it < 4; it++) {
        int n0 = (blockIdx.y * 4 + it) * 128 + wn * 64;

        bf16x8 Bf[4][2];
#pragma unroll
        for (int jn = 0; jn < 4; jn++)
#pragma unroll
            for (int h = 0; h < 2; h++)
                Bf[jn][h] = zfv[(size_t)(n0 + jn * 16 + l16) * 8 + h * 4 + lq];

        // belong loads: float4 per (im, jn), nontemporal (read-once stream)
        f32x4 bl[2][4];
#pragma unroll
        for (int im = 0; im < 2; im++)
#pragma unroll
            for (int jn = 0; jn < 4; jn++) {
                const f32x4* bp = reinterpret_cast<const f32x4*>(
                    belong + (size_t)(n0 + jn * 16 + l16) * MM + (m0 + im * 16 + lq * 4));
                bl[im][jn] = __builtin_nontemporal_load(bp);
            }

        float zn2v[4];
#pragma unroll
        for (int jn = 0; jn < 4; jn++)
            zn2v[jn] = zn2[n0 + jn * 16 + l16];

        f32x4 acc[2][4];
#pragma unroll
        for (int im = 0; im < 2; im++)
#pragma unroll
            for (int jn = 0; jn < 4; jn++) {
                acc[im][jn] = (f32x4){0.f, 0.f, 0.f, 0.f};
                acc[im][jn] = __builtin_amdgcn_mfma_f32_16x16x32_bf16(Af[im][0], Bf[jn][0], acc[im][jn], 0, 0, 0);
                acc[im][jn] = __builtin_amdgcn_mfma_f32_16x16x32_bf16(Af[im][1], Bf[jn][1], acc[im][jn], 0, 0, 0);
            }

#pragma unroll
        for (int im = 0; im < 2; im++)
#pragma unroll
            for (int jn = 0; jn < 4; jn++)
#pragma unroll
                for (int r = 0; r < 4; r++) {
                    float d2 = fmaxf(en2v[im][r] + zn2v[jn] - 2.f * acc[im][jn][r], 0.f);
                    float b = bl[im][jn][r];
                    vmax2[im][r] = fmaxf(vmax2[im][r], b * b * d2);
                    vmin2[im][r] = fminf(vmin2[im][r], d2);
                }
    }

    // reduce across the 16 l16 lanes (n direction) — once per block
#pragma unroll
    for (int off = 1; off < 16; off <<= 1)
#pragma unroll
        for (int im = 0; im < 2; im++)
#pragma unroll
            for (int r = 0; r < 4; r++) {
                vmax2[im][r] = fmaxf(vmax2[im][r], __shfl_xor(vmax2[im][r], off));
                vmin2[im][r] = fminf(vmin2[im][r], __shfl_xor(vmin2[im][r], off));
            }

    __shared__ unsigned smax[64], smin[64];
    if (tid < 64) { smax[tid] = 0u; smin[tid] = 0x7f800000u; }
    __syncthreads();
    if (l16 == 0) {
#pragma unroll
        for (int im = 0; im < 2; im++)
#pragma unroll
            for (int r = 0; r < 4; r++) {
                int ml = wm * 32 + im * 16 + lq * 4 + r;
                atomicMax(&smax[ml], __float_as_uint(sqrtf(vmax2[im][r])));
                atomicMin(&smin[ml], __float_as_uint(sqrtf(vmin2[im][r])));
            }
    }
    __syncthreads();
    if (tid < 64) {
        atomicMax(&bmax[blockIdx.x * 64 + tid], smax[tid]);
        atomicMin(&dmin[blockIdx.x * 64 + tid], smin[tid]);
    }
}

// ---------------------------------------------------------------------------
// k_pass2: recompute d^2 (original orientation: D col = m), inline the
// new_max/ref computation per block. Each block PERSISTS over 4 n-tiles
// (grid 8192 -> 2048): B-fragments (ebf) + en2 + nm^2 + ref hoisted;
// exp-sums accumulated in registers across tiles; shuffle reduce + shared
// reduce + global atomicAdd once per block (1.05M -> 262K atomicAdds).
// Block x==0 materializes refs[] for k_final.
// ---------------------------------------------------------------------------
__global__ __launch_bounds__(256) void k_pass2(const __hip_bfloat16* __restrict__ zf,
                                               const __hip_bfloat16* __restrict__ ebf,
                                               const float* __restrict__ zn2,
                                               const float* __restrict__ en2,
                                               const unsigned* __restrict__ bmax,
                                               const unsigned* __restrict__ dmin,
                                               const float* __restrict__ max_distance,
                                               const float* __restrict__ log_sigma,
                                               const int* __restrict__ pp,
                                               float* __restrict__ refs,
                                               float* __restrict__ sume) {
    __shared__ float snm2[128], sref[128], ssum[128];
    int tid = threadIdx.x;
    int wave = tid >> 6, lane = tid & 63;
    int l16 = lane & 15, lq = lane >> 4;
    int wn = wave >> 1, wm = wave & 1;
    int m0 = blockIdx.y * 128 + wm * 64;

    int p = pp[0];
    float alpha = -0.5f * __expf(-2.f * log_sigma[0]);

    if (tid < 128) {
        int m = blockIdx.y * 128 + tid;
        float bm = __uint_as_float(bmax[m]);
        float dm = __uint_as_float(dmin[m]);
        float nm = fmaxf(EMA_C * max_distance[m] + (1.f - EMA_C) * bm, EPS_C);
        float tlow;
        if (p == 2) {
            float d4  = (dm * dm) * (dm * dm);
            float nm4 = (nm * nm) * (nm * nm);
            tlow = (dm < nm) ? fminf(dm, nm4) : d4;
        } else {
            float e1 = 2.f / (float)p, e2 = 2.f * (float)p;
            tlow = (dm < nm) ? fminf(powf(dm, e1), powf(nm, e2)) : powf(dm, e2);
        }
        float rf = alpha * tlow;   // alpha<0, t>=tlow => s<=rf (no overflow)
        snm2[tid] = nm * nm;
        sref[tid] = rf;
        ssum[tid] = 0.f;
        if (blockIdx.x == 0) refs[m] = rf;
    }
    __syncthreads();

    const bf16x8* zfv = reinterpret_cast<const bf16x8*>(zf);
    const bf16x8* ebv = reinterpret_cast<const bf16x8*>(ebf);

    // n-invariant: B fragments (ebf rows m) + per-m scalars
    bf16x8 Bf[4][2];
#pragma unroll
    for (int j = 0; j < 4; j++)
#pragma unroll
        for (int h = 0; h < 2; h++)
            Bf[j][h] = ebv[(size_t)(m0 + j * 16 + l16) * 8 + h * 4 + lq];
    float en2s[4], nm2s[4], rfs[4];
#pragma unroll
    for (int j = 0; j < 4; j++) {
        en2s[j] = en2[m0 + j * 16 + l16];
        nm2s[j] = snm2[wm * 64 + j * 16 + l16];
        rfs[j]  = sref[wm * 64 + j * 16 + l16];
    }

    bool p2 = (p == 2);
    float pe = (float)p, pi = 1.f / (float)p;

    float csum[4] = {0.f, 0.f, 0.f, 0.f};

#pragma unroll 1
    for (int it = 0; it < 4; it++) {
        int n0 = blockIdx.x * 256 + it * 64 + wn * 32;

        bf16x8 Af[2][2];
#pragma unroll
        for (int i = 0; i < 2; i++)
#pragma unroll
            for (int h = 0; h < 2; h++)
                Af[i][h] = zfv[(size_t)(n0 + i * 16 + l16) * 8 + h * 4 + lq];

        f32x4 acc[2][4];
#pragma unroll
        for (int i = 0; i < 2; i++)
#pragma unroll
            for (int j = 0; j < 4; j++) {
                acc[i][j] = (f32x4){0.f, 0.f, 0.f, 0.f};
                acc[i][j] = __builtin_amdgcn_mfma_f32_16x16x32_bf16(Af[i][0], Bf[j][0], acc[i][j], 0, 0, 0);
                acc[i][j] = __builtin_amdgcn_mfma_f32_16x16x32_bf16(Af[i][1], Bf[j][1], acc[i][j], 0, 0, 0);
            }

        f32x4 zn2v[2];
#pragma unroll
        for (int i = 0; i < 2; i++)
            zn2v[i] = *reinterpret_cast<const f32x4*>(zn2 + n0 + i * 16 + lq * 4);

#pragma unroll
        for (int j = 0; j < 4; j++) {
            float en2v = en2s[j];
            float nm2v = nm2s[j];
            float rfv  = rfs[j];
#pragma unroll
            for (int i = 0; i < 2; i++)
#pragma unroll
                for (int r = 0; r < 4; r++) {
                    float d2c = fmaxf(zn2v[i][r] + en2v - 2.f * acc[i][j][r], 0.f);
                    float t;
                    if (p2) t = (d2c < nm2v) ? sqrtf(d2c) : d2c * d2c;   // d^1 / d^4
                    else    t = powf(d2c, (d2c < nm2v) ? pi : pe);       // (d^2)^(1/p) / (d^2)^p
                    csum[j] += __expf(fmaf(alpha, t, -rfv));
                }
        }
    }

    // reduce over lq groups (n direction) — once per block
#pragma unroll
    for (int j = 0; j < 4; j++) {
        csum[j] += __shfl_xor(csum[j], 16);
        csum[j] += __shfl_xor(csum[j], 32);
        if (lane < 16) atomicAdd(&ssum[wm * 64 + j * 16 + lane], csum[j]);
    }
    __syncthreads();
    if (tid < 128) atomicAdd(&sume[blockIdx.y * 128 + tid], ssum[tid]);
}

// ---------------------------------------------------------------------------
// k_final: loss = -mean(ref + log(sum_exp)) + z_dim * log_sigma
// ---------------------------------------------------------------------------
__global__ __launch_bounds__(256) void k_final(const float* __restrict__ refs,
                                               const float* __restrict__ sume,
                                               const float* __restrict__ log_sigma,
                                               float* __restrict__ out) {
    __shared__ float red[4];
    int tid = threadIdx.x;
    float a = 0.f;
    for (int m = tid; m < MM; m += 256)
        a += refs[m] + logf(fmaxf(sume[m], 1e-30f));
    for (int off = 32; off; off >>= 1) a += __shfl_xor(a, off);
    int wave = tid >> 6, lane = tid & 63;
    if (lane == 0) red[wave] = a;
    __syncthreads();
    if (tid == 0) {
        float t = red[0] + red[1] + red[2] + red[3];
        out[0] = -t / (float)MM + (float)ZD * log_sigma[0];
    }
}

// ---------------------------------------------------------------------------
extern "C" void kernel_launch(void* const* d_in, const int* in_sizes, int n_in,
                              void* d_out, int out_size, void* d_ws, size_t ws_size,
                              hipStream_t stream) {
    const float* z            = (const float*)d_in[0];
    const float* e            = (const float*)d_in[1];
    const float* belong       = (const float*)d_in[2];
    const float* log_sigma    = (const float*)d_in[3];
    const float* max_distance = (const float*)d_in[4];
    const int*   pp           = (const int*)d_in[5];
    float* out = (float*)d_out;

    char* ws = (char*)d_ws;
    __hip_bfloat16* zf  = (__hip_bfloat16*)(ws + 0);        // 2,097,152 B
    __hip_bfloat16* ebf = (__hip_bfloat16*)(ws + 2097152);  //   524,288 B
    float*    zn2  = (float*)(ws + 2621440);                //    65,536 B
    float*    en2  = (float*)(ws + 2686976);                //    16,384 B
    unsigned* bmax = (unsigned*)(ws + 2703360);             //    16,384 B
    unsigned* dmin = (unsigned*)(ws + 2719744);             //    16,384 B
    float*    refs = (float*)(ws + 2736128);                //    16,384 B
    float*    sume = (float*)(ws + 2752512);                //    16,384 B

    k_prep<<<1280, 256, 0, stream>>>(z, e, zf, ebf, zn2, en2, bmax, dmin, sume);
    k_pass1<<<dim3(MM / 64, NN / 512), 256, 0, stream>>>(zf, ebf, zn2, en2, belong, bmax, dmin);
    k_pass2<<<dim3(NN / 256, MM / 128), 256, 0, stream>>>(zf, ebf, zn2, en2, bmax, dmin,
                                                          max_distance, log_sigma, pp, refs, sume);
    k_final<<<1, 256, 0, stream>>>(refs, sume, log_sigma, out);
}

// Round 2
// 449.671 us; speedup vs baseline: 1.0004x; 1.0004x over previous
//
#include <hip/hip_runtime.h>
#include <hip/hip_bf16.h>

// Problem constants (setup_inputs fixed: B=16, z_dim=64, H=W=32, M=4096)
#define ZD   64
#define MM   4096
#define NN   16384
#define HWSZ 1024
#define BB   16

typedef __bf16 bf16x8 __attribute__((ext_vector_type(8)));
typedef float  f32x4  __attribute__((ext_vector_type(4)));

#define EMA_C 0.999f
#define EPS_C 1e-8f

// ---------------------------------------------------------------------------
// k_prep (merged): blocks [0,256): z transpose->bf16 + zn2
//                  blocks [256,1280): e->bf16 + en2 + accumulator init
// ---------------------------------------------------------------------------
__global__ __launch_bounds__(256) void k_prep(const float* __restrict__ z,
                                              const float* __restrict__ e,
                                              __hip_bfloat16* __restrict__ zf,
                                              __hip_bfloat16* __restrict__ ebf,
                                              float* __restrict__ zn2,
                                              float* __restrict__ en2,
                                              unsigned* __restrict__ bmax,
                                              unsigned* __restrict__ dmin,
                                              float* __restrict__ sume) {
    __shared__ float tile[64][65];
    __shared__ float part[4][64];
    int blk = blockIdx.x;
    int tid = threadIdx.x;
    if (blk < 256) {
        // ---- z prep: b = blk>>4, hw-tile = blk&15 ----
        int b   = blk >> 4;
        int hw0 = (blk & 15) * 64;
        int tx = tid & 63, ty = tid >> 6;
        const float* zp = z + (size_t)b * (ZD * HWSZ);
#pragma unroll
        for (int kk = 0; kk < 16; kk++) {
            int k = kk * 4 + ty;
            tile[k][tx] = zp[(size_t)k * HWSZ + hw0 + tx];  // coalesced
        }
        __syncthreads();
#pragma unroll
        for (int i = 0; i < 16; i++) {   // coalesced bf16 row writes
            int li = tid + i * 256;
            int ln = li >> 6, lk = li & 63;
            int n = b * HWSZ + hw0 + ln;
            zf[(size_t)n * ZD + lk] = __float2bfloat16(tile[lk][ln]);
        }
        float s = 0.f;
#pragma unroll
        for (int kk = 0; kk < 16; kk++) {
            float q = __bfloat162float(__float2bfloat16(tile[ty * 1 + kk * 4][tx]));
            s += q * q;
        }
        part[ty][tx] = s;
        __syncthreads();
        if (tid < 64) {
            float t = part[0][tid] + part[1][tid] + part[2][tid] + part[3][tid];
            zn2[b * HWSZ + hw0 + tid] = t;
        }
    } else {
        // ---- e prep + init ----
        int eb  = blk - 256;            // 0..1023
        int gid = eb * 256 + tid;
        if (gid < MM) {                 // ws is poisoned 0xAA each launch
            bmax[gid] = 0u;             // belong*d >= 0 -> uint max works
            dmin[gid] = 0x7f800000u;    // +inf
            sume[gid] = 0.f;
        }
        int wave = tid >> 6, lane = tid & 63;
        int row = eb * 4 + wave;
        if (row < MM) {
            float v = e[row * ZD + lane];
            __hip_bfloat16 b16 = __float2bfloat16(v);
            ebf[row * ZD + lane] = b16;
            float q = __bfloat162float(b16);  // norm from quantized value
            float s = q * q;
            for (int off = 32; off; off >>= 1) s += __shfl_xor(s, off);
            if (lane == 0) en2[row] = s;
        }
    }
}

// ---------------------------------------------------------------------------
// k_pass1 helpers
// ---------------------------------------------------------------------------
__device__ __forceinline__ void load_bl(const float* __restrict__ belong,
                                        int n0, int m0, int l16, int lq,
                                        f32x4 (&bl)[2][4]) {
#pragma unroll
    for (int im = 0; im < 2; im++)
#pragma unroll
        for (int jn = 0; jn < 4; jn++) {
            const f32x4* bp = reinterpret_cast<const f32x4*>(
                belong + (size_t)(n0 + jn * 16 + l16) * MM + (m0 + im * 16 + lq * 4));
            bl[im][jn] = __builtin_nontemporal_load(bp);
        }
}

__device__ __forceinline__ void p1_tile(const bf16x8* __restrict__ zfv,
                                        const float* __restrict__ zn2,
                                        int n0, int l16, int lq,
                                        const bf16x8 (&Af)[2][2],
                                        const f32x4 (&en2v)[2],
                                        const f32x4 (&bl)[2][4],
                                        float (&vmax2)[2][4],
                                        float (&vmin2)[2][4]) {
    bf16x8 Bf[4][2];
#pragma unroll
    for (int jn = 0; jn < 4; jn++)
#pragma unroll
        for (int h = 0; h < 2; h++)
            Bf[jn][h] = zfv[(size_t)(n0 + jn * 16 + l16) * 8 + h * 4 + lq];

    float zn2v[4];
#pragma unroll
    for (int jn = 0; jn < 4; jn++)
        zn2v[jn] = zn2[n0 + jn * 16 + l16];

    f32x4 acc[2][4];
#pragma unroll
    for (int im = 0; im < 2; im++)
#pragma unroll
        for (int jn = 0; jn < 4; jn++) {
            acc[im][jn] = (f32x4){0.f, 0.f, 0.f, 0.f};
            acc[im][jn] = __builtin_amdgcn_mfma_f32_16x16x32_bf16(Af[im][0], Bf[jn][0], acc[im][jn], 0, 0, 0);
            acc[im][jn] = __builtin_amdgcn_mfma_f32_16x16x32_bf16(Af[im][1], Bf[jn][1], acc[im][jn], 0, 0, 0);
        }

#pragma unroll
    for (int im = 0; im < 2; im++)
#pragma unroll
        for (int jn = 0; jn < 4; jn++)
#pragma unroll
            for (int r = 0; r < 4; r++) {
                float d2 = fmaxf(en2v[im][r] + zn2v[jn] - 2.f * acc[im][jn][r], 0.f);
                float b = bl[im][jn][r];
                vmax2[im][r] = fmaxf(vmax2[im][r], b * b * d2);
                vmin2[im][r] = fminf(vmin2[im][r], d2);
            }
}

// ---------------------------------------------------------------------------
// k_pass1: SWAPPED operand order (A = ebf rows m, B = zf rows n) so that
// D: row = m = lq*4 + reg ; col = n = l16.
// Each block PERSISTS over 8 n-tiles (grid 1024 blocks):
//  - belong loads REGISTER DOUBLE-BUFFERED (tile it+1/it+2 issued before the
//    epilogue of tile it) so each wave keeps ~2 KB of HBM traffic in flight;
//    at 8 waves/CU this exceeds the ~10 B/cyc/CU needed to saturate HBM.
//  - running max/min in registers, tracking (b*d)^2 and d^2 (sqrt deferred)
//  - shuffle tree + shared reduce + global atomics ONCE per block (131K total)
// __launch_bounds__(256,2) pins VGPR <= 256 so the 2nd buffer can't drop
// occupancy to 1 wave/SIMD.
// ---------------------------------------------------------------------------
__global__ __launch_bounds__(256, 2) void k_pass1(const __hip_bfloat16* __restrict__ zf,
                                                  const __hip_bfloat16* __restrict__ ebf,
                                                  const float* __restrict__ zn2,
                                                  const float* __restrict__ en2,
                                                  const float* __restrict__ belong,
                                                  unsigned* __restrict__ bmax,
                                                  unsigned* __restrict__ dmin) {
    int tid = threadIdx.x;
    int wave = tid >> 6, lane = tid & 63;
    int l16 = lane & 15, lq = lane >> 4;
    int wm = wave & 1, wn = wave >> 1;
    int m0 = blockIdx.x * 64 + wm * 32;
    int nbase = blockIdx.y * 1024 + wn * 64;   // 8 tiles of 128 per block

    const bf16x8* ebv = reinterpret_cast<const bf16x8*>(ebf);
    const bf16x8* zfv = reinterpret_cast<const bf16x8*>(zf);

    // n-invariant: A fragments (ebf rows m) + en2
    bf16x8 Af[2][2];
#pragma unroll
    for (int im = 0; im < 2; im++)
#pragma unroll
        for (int h = 0; h < 2; h++)
            Af[im][h] = ebv[(size_t)(m0 + im * 16 + l16) * 8 + h * 4 + lq];
    f32x4 en2v[2];
#pragma unroll
    for (int im = 0; im < 2; im++)
        en2v[im] = *reinterpret_cast<const f32x4*>(en2 + m0 + im * 16 + lq * 4);

    float vmax2[2][4], vmin2[2][4];   // (belong*d)^2 and d^2 running extrema
#pragma unroll
    for (int im = 0; im < 2; im++)
#pragma unroll
        for (int r = 0; r < 4; r++) { vmax2[im][r] = 0.f; vmin2[im][r] = 3.4e38f; }

    f32x4 blA[2][4], blB[2][4];
    load_bl(belong, nbase + 0 * 128, m0, l16, lq, blA);
    load_bl(belong, nbase + 1 * 128, m0, l16, lq, blB);

#pragma unroll 1
    for (int it = 0; it < 8; it += 2) {
        p1_tile(zfv, zn2, nbase + it * 128, l16, lq, Af, en2v, blA, vmax2, vmin2);
        if (it + 2 < 8) load_bl(belong, nbase + (it + 2) * 128, m0, l16, lq, blA);
        p1_tile(zfv, zn2, nbase + (it + 1) * 128, l16, lq, Af, en2v, blB, vmax2, vmin2);
        if (it + 3 < 8) load_bl(belong, nbase + (it + 3) * 128, m0, l16, lq, blB);
    }

    // reduce across the 16 l16 lanes (n direction) — once per block
#pragma unroll
    for (int off = 1; off < 16; off <<= 1)
#pragma unroll
        for (int im = 0; im < 2; im++)
#pragma unroll
            for (int r = 0; r < 4; r++) {
                vmax2[im][r] = fmaxf(vmax2[im][r], __shfl_xor(vmax2[im][r], off));
                vmin2[im][r] = fminf(vmin2[im][r], __shfl_xor(vmin2[im][r], off));
            }

    __shared__ unsigned smax[64], smin[64];
    if (tid < 64) { smax[tid] = 0u; smin[tid] = 0x7f800000u; }
    __syncthreads();
    if (l16 == 0) {
#pragma unroll
        for (int im = 0; im < 2; im++)
#pragma unroll
            for (int r = 0; r < 4; r++) {
                int ml = wm * 32 + im * 16 + lq * 4 + r;
                atomicMax(&smax[ml], __float_as_uint(sqrtf(vmax2[im][r])));
                atomicMin(&smin[ml], __float_as_uint(sqrtf(vmin2[im][r])));
            }
    }
    __syncthreads();
    if (tid < 64) {
        atomicMax(&bmax[blockIdx.x * 64 + tid], smax[tid]);
        atomicMin(&dmin[blockIdx.x * 64 + tid], smin[tid]);
    }
}

// ---------------------------------------------------------------------------
// k_pass2: recompute d^2 (original orientation: D col = m), inline the
// new_max/ref computation per block. Each block PERSISTS over 4 n-tiles
// (grid 2048): B-fragments (ebf) + en2 + nm^2 + ref hoisted; exp-sums
// accumulated in registers across tiles; reductions + global atomicAdd once
// per block. Block x==0 materializes refs[] for k_final.
// ---------------------------------------------------------------------------
__global__ __launch_bounds__(256) void k_pass2(const __hip_bfloat16* __restrict__ zf,
                                               const __hip_bfloat16* __restrict__ ebf,
                                               const float* __restrict__ zn2,
                                               const float* __restrict__ en2,
                                               const unsigned* __restrict__ bmax,
                                               const unsigned* __restrict__ dmin,
                                               const float* __restrict__ max_distance,
                                               const float* __restrict__ log_sigma,
                                               const int* __restrict__ pp,
                                               float* __restrict__ refs,
                                               float* __restrict__ sume) {
    __shared__ float snm2[128], sref[128], ssum[128];
    int tid = threadIdx.x;
    int wave = tid >> 6, lane = tid & 63;
    int l16 = lane & 15, lq = lane >> 4;
    int wn = wave >> 1, wm = wave & 1;
    int m0 = blockIdx.y * 128 + wm * 64;

    int p = pp[0];
    float alpha = -0.5f * __expf(-2.f * log_sigma[0]);

    if (tid < 128) {
        int m = blockIdx.y * 128 + tid;
        float bm = __uint_as_float(bmax[m]);
        float dm = __uint_as_float(dmin[m]);
        float nm = fmaxf(EMA_C * max_distance[m] + (1.f - EMA_C) * bm, EPS_C);
        float tlow;
        if (p == 2) {
            float d4  = (dm * dm) * (dm * dm);
            float nm4 = (nm * nm) * (nm * nm);
            tlow = (dm < nm) ? fminf(dm, nm4) : d4;
        } else {
            float e1 = 2.f / (float)p, e2 = 2.f * (float)p;
            tlow = (dm < nm) ? fminf(powf(dm, e1), powf(nm, e2)) : powf(dm, e2);
        }
        float rf = alpha * tlow;   // alpha<0, t>=tlow => s<=rf (no overflow)
        snm2[tid] = nm * nm;
        sref[tid] = rf;
        ssum[tid] = 0.f;
        if (blockIdx.x == 0) refs[m] = rf;
    }
    __syncthreads();

    const bf16x8* zfv = reinterpret_cast<const bf16x8*>(zf);
    const bf16x8* ebv = reinterpret_cast<const bf16x8*>(ebf);

    // n-invariant: B fragments (ebf rows m) + per-m scalars
    bf16x8 Bf[4][2];
#pragma unroll
    for (int j = 0; j < 4; j++)
#pragma unroll
        for (int h = 0; h < 2; h++)
            Bf[j][h] = ebv[(size_t)(m0 + j * 16 + l16) * 8 + h * 4 + lq];
    float en2s[4], nm2s[4], rfs[4];
#pragma unroll
    for (int j = 0; j < 4; j++) {
        en2s[j] = en2[m0 + j * 16 + l16];
        nm2s[j] = snm2[wm * 64 + j * 16 + l16];
        rfs[j]  = sref[wm * 64 + j * 16 + l16];
    }

    bool p2 = (p == 2);
    float pe = (float)p, pi = 1.f / (float)p;

    float csum[4] = {0.f, 0.f, 0.f, 0.f};

#pragma unroll 1
    for (int it = 0; it < 4; it++) {
        int n0 = blockIdx.x * 256 + it * 64 + wn * 32;

        bf16x8 Af[2][2];
#pragma unroll
        for (int i = 0; i < 2; i++)
#pragma unroll
            for (int h = 0; h < 2; h++)
                Af[i][h] = zfv[(size_t)(n0 + i * 16 + l16) * 8 + h * 4 + lq];

        f32x4 acc[2][4];
#pragma unroll
        for (int i = 0; i < 2; i++)
#pragma unroll
            for (int j = 0; j < 4; j++) {
                acc[i][j] = (f32x4){0.f, 0.f, 0.f, 0.f};
                acc[i][j] = __builtin_amdgcn_mfma_f32_16x16x32_bf16(Af[i][0], Bf[j][0], acc[i][j], 0, 0, 0);
                acc[i][j] = __builtin_amdgcn_mfma_f32_16x16x32_bf16(Af[i][1], Bf[j][1], acc[i][j], 0, 0, 0);
            }

        f32x4 zn2v[2];
#pragma unroll
        for (int i = 0; i < 2; i++)
            zn2v[i] = *reinterpret_cast<const f32x4*>(zn2 + n0 + i * 16 + lq * 4);

#pragma unroll
        for (int j = 0; j < 4; j++) {
            float en2v = en2s[j];
            float nm2v = nm2s[j];
            float rfv  = rfs[j];
#pragma unroll
            for (int i = 0; i < 2; i++)
#pragma unroll
                for (int r = 0; r < 4; r++) {
                    float d2c = fmaxf(zn2v[i][r] + en2v - 2.f * acc[i][j][r], 0.f);
                    float t;
                    if (p2) t = (d2c < nm2v) ? sqrtf(d2c) : d2c * d2c;   // d^1 / d^4
                    else    t = powf(d2c, (d2c < nm2v) ? pi : pe);       // (d^2)^(1/p) / (d^2)^p
                    csum[j] += __expf(fmaf(alpha, t, -rfv));
                }
        }
    }

    // reduce over lq groups (n direction) — once per block
#pragma unroll
    for (int j = 0; j < 4; j++) {
        csum[j] += __shfl_xor(csum[j], 16);
        csum[j] += __shfl_xor(csum[j], 32);
        if (lane < 16) atomicAdd(&ssum[wm * 64 + j * 16 + lane], csum[j]);
    }
    __syncthreads();
    if (tid < 128) atomicAdd(&sume[blockIdx.y * 128 + tid], ssum[tid]);
}

// ---------------------------------------------------------------------------
// k_final: loss = -mean(ref + log(sum_exp)) + z_dim * log_sigma
// ---------------------------------------------------------------------------
__global__ __launch_bounds__(256) void k_final(const float* __restrict__ refs,
                                               const float* __restrict__ sume,
                                               const float* __restrict__ log_sigma,
                                               float* __restrict__ out) {
    __shared__ float red[4];
    int tid = threadIdx.x;
    float a = 0.f;
    for (int m = tid; m < MM; m += 256)
        a += refs[m] + logf(fmaxf(sume[m], 1e-30f));
    for (int off = 32; off; off >>= 1) a += __shfl_xor(a, off);
    int wave = tid >> 6, lane = tid & 63;
    if (lane == 0) red[wave] = a;
    __syncthreads();
    if (tid == 0) {
        float t = red[0] + red[1] + red[2] + red[3];
        out[0] = -t / (float)MM + (float)ZD * log_sigma[0];
    }
}

// ---------------------------------------------------------------------------
extern "C" void kernel_launch(void* const* d_in, const int* in_sizes, int n_in,
                              void* d_out, int out_size, void* d_ws, size_t ws_size,
                              hipStream_t stream) {
    const float* z            = (const float*)d_in[0];
    const float* e            = (const float*)d_in[1];
    const float* belong       = (const float*)d_in[2];
    const float* log_sigma    = (const float*)d_in[3];
    const float* max_distance = (const float*)d_in[4];
    const int*   pp           = (const int*)d_in[5];
    float* out = (float*)d_out;

    char* ws = (char*)d_ws;
    __hip_bfloat16* zf  = (__hip_bfloat16*)(ws + 0);        // 2,097,152 B
    __hip_bfloat16* ebf = (__hip_bfloat16*)(ws + 2097152);  //   524,288 B
    float*    zn2  = (float*)(ws + 2621440);                //    65,536 B
    float*    en2  = (float*)(ws + 2686976);                //    16,384 B
    unsigned* bmax = (unsigned*)(ws + 2703360);             //    16,384 B
    unsigned* dmin = (unsigned*)(ws + 2719744);             //    16,384 B
    float*    refs = (float*)(ws + 2736128);                //    16,384 B
    float*    sume = (float*)(ws + 2752512);                //    16,384 B

    k_prep<<<1280, 256, 0, stream>>>(z, e, zf, ebf, zn2, en2, bmax, dmin, sume);
    k_pass1<<<dim3(MM / 64, NN / 1024), 256, 0, stream>>>(zf, ebf, zn2, en2, belong, bmax, dmin);
    k_pass2<<<dim3(NN / 256, MM / 128), 256, 0, stream>>>(zf, ebf, zn2, en2, bmax, dmin,
                                                          max_distance, log_sigma, pp, refs, sume);
    k_final<<<1, 256, 0, stream>>>(refs, sume, log_sigma, out);
}